// Round 3
// baseline (159.661 us; speedup 1.0000x reference)
//
#include <hip/hip_runtime.h>

// Problem constants: nframes=8, nloc=8192, nnei=128, nall=16384, ntypes=4,
// nspline=2000. rmin=0, hh=f32(0.005), rcut=6.0.
constexpr int NFRAMES = 8;
constexpr int NLOC    = 8192;
constexpr int NNEI    = 128;
constexpr int NALL    = 16384;
constexpr int NTYPES  = 4;
constexpr int NSPLINE = 2000;
constexpr int KLIVE   = 1200;   // rr<6 => uu=rr*200<1200 => live bins [0,1200)
constexpr int KBLK    = 8;      // old lds kernel: chunks per bucket

// r19 chunk-in-grid parameters
constexpr int CHUNK   = 4096;         // atoms per staged pack chunk (64 KiB)
constexpr int NCHUNK  = NALL / CHUNK; // 4
constexpr int SLICES  = 2;            // 32 buckets x 4 chunks x 2 = 256 blocks

// Opaque dataflow barrier: keeps the verified f32 rounding chain intact.
#define FP_BAR(x) asm volatile("" : "+v"(x))

__global__ __launch_bounds__(256) void pack_kernel(
    const float* __restrict__ coord, const int* __restrict__ atype,
    float4* __restrict__ pack, int* __restrict__ cnts,
    float* __restrict__ outz)
{
    int t = blockIdx.x * 256 + threadIdx.x;   // grid sized exactly (131072)
    if (blockIdx.x == 0 && threadIdx.x < NFRAMES * NTYPES) cnts[threadIdx.x] = 0;
    if (t < NFRAMES * NLOC) outz[t] = 0.f;    // r19: out is atomic-accumulated
    float4 v;
    v.x = coord[3 * (size_t)t + 0];
    v.y = coord[3 * (size_t)t + 1];
    v.z = coord[3 * (size_t)t + 2];
    v.w = __int_as_float(atype[t]);
    pack[t] = v;
}

// Two-level aggregation (r14, ~3us): LDS histogram, 1 global atomic per
// (block,type), then scatter.
__global__ __launch_bounds__(256) void bucket_kernel(
    const int* __restrict__ atype, int* __restrict__ perm,
    int* __restrict__ cnts)
{
    __shared__ int hist[NTYPES];
    __shared__ int base[NTYPES];
    const int t = blockIdx.x * 256 + threadIdx.x;   // 0..65535
    const int f = t >> 13;                          // block-uniform (256|8192)
    const int i = t & (NLOC - 1);
    const int ty = atype[(size_t)f * NALL + i];

    if (threadIdx.x < NTYPES) hist[threadIdx.x] = 0;
    __syncthreads();
    const int my_off = atomicAdd(&hist[ty], 1);     // LDS atomic (fast)
    __syncthreads();
    if (threadIdx.x < NTYPES)
        base[threadIdx.x] = atomicAdd(&cnts[f * NTYPES + threadIdx.x],
                                      hist[threadIdx.x]);
    __syncthreads();
    perm[(size_t)(f * NTYPES + ty) * NLOC + base[ty] + my_off] = i;
}

// r19 compact: one 32-lane half per row; int4 loads (4 comps/lane), ballot
// partition by chunk into an LDS row buffer, coalesced int4 flush. Output
// row = valid neighbors grouped by chunk (j>>12), invalid dropped, stored as
// ushort within-chunk index (j&4095). Order within a sublist is irrelevant
// (f64 accumulation). offs[row] = prefix ends.
__global__ __launch_bounds__(256) void compact_kernel(
    const int* __restrict__ nlist, ushort* __restrict__ cl,
    int4* __restrict__ offs)
{
    __shared__ alignas(16) ushort srow[8][128];
    const int hr  = threadIdx.x >> 5;               // half-row 0..7
    const int lih = threadIdx.x & 31;
    const int w   = blockIdx.x * 8 + hr;            // row 0..65535
    const int* __restrict__ row = nlist + (size_t)w * NNEI;
    const int4 j4 = ((const int4*)row)[lih];        // comps 4*lih..4*lih+3
    const uint lt = (1u << lih) - 1u;
    const int hsh = (hr & 1) * 32;                  // this half's ballot shift
    int base = 0;
    int e[NCHUNK];
#pragma unroll
    for (int c = 0; c < NCHUNK; ++c) {
        const bool m0 = (j4.x >= 0) && ((j4.x >> 12) == c);
        const bool m1 = (j4.y >= 0) && ((j4.y >> 12) == c);
        const bool m2 = (j4.z >= 0) && ((j4.z >> 12) == c);
        const bool m3 = (j4.w >= 0) && ((j4.w >> 12) == c);
        const uint b0 = (uint)(__ballot(m0) >> hsh);
        const uint b1 = (uint)(__ballot(m1) >> hsh);
        const uint b2 = (uint)(__ballot(m2) >> hsh);
        const uint b3 = (uint)(__ballot(m3) >> hsh);
        const int n0 = __popc(b0), n1 = __popc(b1), n2 = __popc(b2);
        if (m0) srow[hr][base + __popc(b0 & lt)] = (ushort)(j4.x & (CHUNK - 1));
        if (m1) srow[hr][base + n0 + __popc(b1 & lt)] =
            (ushort)(j4.y & (CHUNK - 1));
        if (m2) srow[hr][base + n0 + n1 + __popc(b2 & lt)] =
            (ushort)(j4.z & (CHUNK - 1));
        if (m3) srow[hr][base + n0 + n1 + n2 + __popc(b3 & lt)] =
            (ushort)(j4.w & (CHUNK - 1));
        base += n0 + n1 + n2 + __popc(b3);
        e[c] = base;
    }
    __syncthreads();   // LDS scatter visible to flush lanes
    if (lih < 16)
        ((int4*)(cl + (size_t)w * NNEI))[lih] = ((const int4*)srow[hr])[lih];
    if (lih == 0) offs[w] = make_int4(e[0], e[1], e[2], e[3]);
}

// VERIFIED ref chain (r11, absmax 3.8e-6 — DO NOT TOUCH):
//   ss = fma(dz,dz, fma(dx,dx, dy*dy)); rr = CR sqrtf; uu = rr * f32(1/hh);
//   idx = trunc(uu); poly/sum in f64 (post-bin). Energy zero iff
//   !valid | rr>=6; live => idx in [0,1199].
// Invalid lanes pass c={0,0,0,0}: dx..ss are finite, valid=false skips ltab.
__device__ __forceinline__ double nb_energy_lds(
    float4 c, bool valid, float xl, float yl, float zl,
    float rmin, float recip, const float4* __restrict__ ltab)
{
    float dx = c.x - xl;  FP_BAR(dx);
    float dy = c.y - yl;  FP_BAR(dy);
    float dz = c.z - zl;  FP_BAR(dz);
    float my = dy * dy;                    FP_BAR(my);
    float t1 = __builtin_fmaf(dx, dx, my); FP_BAR(t1);   // canonical inner
    float ss = __builtin_fmaf(dz, dz, t1); FP_BAR(ss);
    float rr = sqrtf(ss);                  FP_BAR(rr);   // CR
    float num = rr - rmin;               FP_BAR(num);    // rmin=0: num==rr
    float uu  = num * recip;             FP_BAR(uu);     // recip-mul form
    double e = 0.0;
    if (valid && rr < 6.0f) {
        int    idx = (int)uu;                // in [0,1199] here
        double t   = (double)uu - (double)idx;           // exact (Sterbenz)
        int    tj  = __float_as_int(c.w);
        float4 cf  = ltab[tj * KLIVE + idx];             // ds_read_b128
        e = (((double)cf.x * t + (double)cf.y) * t + (double)cf.z) * t
            + (double)cf.w;
    }
    return e;
}

// r19 main kernel: chunk-in-grid. Block = (bucket, chunk, slice): stages ltab
// (76.8KB) + ONE cpack chunk (64KB) and computes per-(loc,chunk) partial
// energies, atomicAdd f32 into self-zeroed out. Staging redundancy drops
// 5.4M->2.3M lane-req; crow range read as few int4s + shfl redistribution
// (~4 lane-req/loc/chunk instead of ~26). All scattered traffic is LDS.
__global__ __launch_bounds__(1024) void pairtab_stream_kernel(
    const float4* __restrict__ pack,
    const float*  __restrict__ tab,       // [NTYPES][NTYPES][NSPLINE][4]
    const float*  __restrict__ tab_info,  // [rmin, hh, nspline, ntypes]
    const ushort* __restrict__ cl,        // chunk-compacted neighbor rows
    const int4*   __restrict__ offs,      // per-row prefix ends
    const int*    __restrict__ perm,      // [32][NLOC] bucketed loc ids
    const int*    __restrict__ cnts,      // [32]
    float*        __restrict__ out)       // [NFRAMES][NLOC], pre-zeroed
{
    __shared__ float4 ltab[NTYPES * KLIVE];   // 76800 B
    __shared__ float4 cpack[CHUNK];           // 65536 B  (142336 total)

    const int blk    = blockIdx.x;
    const int slice  = blk & (SLICES - 1);
    const int c      = (blk >> 1) & (NCHUNK - 1);
    const int bucket = blk >> 3;              // 0..31
    const int f  = bucket >> 2;
    const int ti = bucket & 3;

    // stage tab[ti][tj][0..1199][:] -> ltab[tj*1200+k] (coalesced float4)
    const float4* tsrc = (const float4*)tab + (size_t)ti * (NTYPES * NSPLINE);
    for (int idx = threadIdx.x; idx < NTYPES * KLIVE; idx += 1024) {
        int tj = idx / KLIVE;
        int k  = idx - tj * KLIVE;
        ltab[idx] = tsrc[tj * NSPLINE + k];
    }
    // stage this block's pack chunk
    {
        const float4* psrc = pack + (size_t)f * NALL + c * CHUNK;
        for (int k = threadIdx.x; k < CHUNK; k += 1024) cpack[k] = psrc[k];
    }
    __syncthreads();

    const float rmin = tab_info[0];
    const float hh   = tab_info[1];
    // CR f32 reciprocal via f64 + single rounding == f32 divide(1,hh) == 200.0f
    float recip = (float)(1.0 / (double)hh);  FP_BAR(recip);

    const int cnt  = cnts[bucket];
    const int lane = threadIdx.x & 63;
    const int wave = (int)(threadIdx.x >> 6); // 0..15
    const int half = lane >> 5;
    const int lih  = lane & 31;
    const int slot = (wave << 1) | half;      // 0..31
    const size_t fb = (size_t)f * NALL;
    const int*    __restrict__ permb = perm + (size_t)bucket * NLOC;
    const int4*   __restrict__ offf  = offs + (size_t)f * NLOC;
    const ushort* __restrict__ clf   = cl   + (size_t)f * NLOC * NNEI;
    const float4 zero4 = make_float4(0.f, 0.f, 0.f, 0.f);

    // s covers this slice's locs: s ≡ slice (mod 2), one loc per half.
    int s = 2 * slot + slice;
    int loc = 0; int4 pe = make_int4(0, 0, 0, 0); float4 pl = zero4;
    if (s < cnt) {
        loc = permb[s];
        pe  = offf[loc];
        pl  = pack[fb + loc];
    }
    while (s < cnt) {
        // prefetch next loc's descriptors (overlaps with energy compute)
        const int sn = s + 64;
        int locn = 0; int4 pen = make_int4(0, 0, 0, 0); float4 pln = zero4;
        if (sn < cnt) {
            locn = permb[sn];
            pen  = offf[locn];
            pln  = pack[fb + locn];
        }

        const int beg = (c == 0) ? 0
                      : ((c == 1) ? pe.x : ((c == 2) ? pe.y : pe.z));
        const int end = (c == 0) ? pe.x
                      : ((c == 1) ? pe.y : ((c == 2) ? pe.z : pe.w));
        const ushort* __restrict__ crow = clf + (size_t)loc * NNEI;

        // vector-load the [beg,end) ushort range: A 16B-aligned, nw int4 words
        const int A  = beg & ~7;
        const int nw = (end - A + 7) >> 3;      // <= 16
        int4 v = make_int4(0, 0, 0, 0);
        if (lih < nw) v = ((const int4*)(crow + A))[lih];

        double es = 0.0;
        const int ng = (end - beg + 31) >> 5;   // 32-entry groups (0 if empty)
        for (int g = 0; g < ng; ++g) {
            // redistribute: lane lih wants entry e = beg + 32g + lih
            const int off  = (beg & 7) + (g << 5) + lih;  // e - A
            const bool lv  = (beg + (g << 5) + lih) < end;
            const int srcl = (half << 5) + (off >> 3);
            const int a0 = __shfl(v.x, srcl, 64);
            const int a1 = __shfl(v.y, srcl, 64);
            const int a2 = __shfl(v.z, srcl, 64);
            const int a3 = __shfl(v.w, srcl, 64);
            const int d  = (off >> 1) & 3;
            const int wd = (d == 0) ? a0 : ((d == 1) ? a1 : ((d == 2) ? a2 : a3));
            const int us = (off & 1) ? ((wd >> 16) & 0xffff) : (wd & 0xffff);
            float4 cc = zero4;
            if (lv) cc = cpack[us];              // LDS gather (ds_read_b128)
            es += nb_energy_lds(cc, lv, pl.x, pl.y, pl.z, rmin, recip, ltab);
        }

        // butterfly within the 32-lane half, one partial per (loc, chunk)
#pragma unroll
        for (int o = 16; o >= 1; o >>= 1)
            es += __shfl_xor(es, o, 64);
        if (lih == 0)
            atomicAdd(&out[(size_t)f * NLOC + loc], (float)(0.5 * es));

        s = sn; loc = locn; pe = pen; pl = pln;
    }
}

// -------- r16 kernel (kept as mid-ws fallback) --------
__global__ __launch_bounds__(1024, 8) void pairtab_lds_kernel(
    const float4* __restrict__ pack,
    const float*  __restrict__ tab,
    const float*  __restrict__ tab_info,
    const int*    __restrict__ nlist,
    const int*    __restrict__ perm,
    const int*    __restrict__ cnts,
    float*        __restrict__ out)
{
    __shared__ float4 ltab[NTYPES * KLIVE];   // 76800 B

    const int bucket = blockIdx.x >> 3;       // / KBLK
    const int chunk  = blockIdx.x & (KBLK - 1);
    const int f  = bucket >> 2;
    const int ti = bucket & 3;

    const float4* tsrc = (const float4*)tab + (size_t)ti * (NTYPES * NSPLINE);
    for (int idx = threadIdx.x; idx < NTYPES * KLIVE; idx += 1024) {
        int tj = idx / KLIVE;
        int k  = idx - tj * KLIVE;
        ltab[idx] = tsrc[tj * NSPLINE + k];
    }
    __syncthreads();

    const float rmin = tab_info[0];
    const float hh   = tab_info[1];
    float recip = (float)(1.0 / (double)hh);  FP_BAR(recip);

    const int cnt  = cnts[bucket];
    const int lane = threadIdx.x & 63;
    const int wave = (int)(threadIdx.x >> 6); // 0..15
    const int half = lane >> 5;
    const int lih  = lane & 31;
    const size_t fb = (size_t)f * NALL;
    const int* __restrict__ permb = perm + (size_t)bucket * NLOC;
    const int* __restrict__ nlf   = nlist + (size_t)f * NLOC * NNEI;
    const float4 zero4 = make_float4(0.f, 0.f, 0.f, 0.f);

    for (int s0 = chunk * 32; s0 < cnt; s0 += KBLK * 32) {
        const int s = s0 + wave * 2 + half;
        const bool active = s < cnt;          // uniform per 32-lane half
        const int loc = active ? permb[s] : 0;

        const float4 pl = pack[fb + loc];     // half-uniform broadcast
        const float xl = pl.x, yl = pl.y, zl = pl.z;

        const int4 jj = ((const int4*)(nlf + (size_t)loc * NNEI))[lih];

        float4 c0 = zero4, c1 = zero4, c2 = zero4, c3 = zero4;
        if (jj.x >= 0) c0 = pack[fb + jj.x];
        if (jj.y >= 0) c1 = pack[fb + jj.y];
        if (jj.z >= 0) c2 = pack[fb + jj.z];
        if (jj.w >= 0) c3 = pack[fb + jj.w];

        double esum = nb_energy_lds(c0, jj.x >= 0, xl, yl, zl, rmin, recip, ltab)
                    + nb_energy_lds(c1, jj.y >= 0, xl, yl, zl, rmin, recip, ltab)
                    + nb_energy_lds(c2, jj.z >= 0, xl, yl, zl, rmin, recip, ltab)
                    + nb_energy_lds(c3, jj.w >= 0, xl, yl, zl, rmin, recip, ltab);

#pragma unroll
        for (int off = 16; off >= 1; off >>= 1)
            esum += __shfl_xor(esum, off, 64);

        if (active && lih == 0) out[(size_t)f * NLOC + loc] = (float)(0.5 * esum);
    }
}

// -------- r12 fallback (used only if ws_size is too small) --------
__device__ __forceinline__ double nb_energy_g(
    float4 c, bool valid, float xl, float yl, float zl,
    float rmin, float recip, const float* __restrict__ tabi)
{
    float dx = c.x - xl;  FP_BAR(dx);
    float dy = c.y - yl;  FP_BAR(dy);
    float dz = c.z - zl;  FP_BAR(dz);
    float my = dy * dy;                    FP_BAR(my);
    float t1 = __builtin_fmaf(dx, dx, my); FP_BAR(t1);
    float ss = __builtin_fmaf(dz, dz, t1); FP_BAR(ss);
    float rr = sqrtf(ss);                  FP_BAR(rr);
    float num = rr - rmin;               FP_BAR(num);
    float uu  = num * recip;             FP_BAR(uu);
    int   idx = (int)uu;
    double t  = (double)uu - (double)idx;
    int clip  = idx < 0 ? 0 : (idx > NSPLINE - 1 ? NSPLINE - 1 : idx);
    int tj    = __float_as_int(c.w);
    const float4 coef =
        *(const float4*)(tabi + (((size_t)tj * NSPLINE + clip) << 2));
    double e = (((double)coef.x * t + (double)coef.y) * t + (double)coef.z) * t
               + (double)coef.w;
    bool zero = (!valid) | (idx > NSPLINE) | (rr >= 6.0f);
    return zero ? 0.0 : e;
}

__global__ __launch_bounds__(256) void pairtab_kernel(
    const float4* __restrict__ pack, const float* __restrict__ tab,
    const float* __restrict__ tab_info, const int* __restrict__ nlist,
    float* __restrict__ out)
{
    const int lane = threadIdx.x & 63;
    const int wid  = (blockIdx.x * 256 + threadIdx.x) >> 6;
    const int half = lane >> 5;
    const int gloc = 2 * wid + half;
    const int f = gloc >> 13;
    const int i = gloc & (NLOC - 1);
    const float rmin = tab_info[0];
    const float hh   = tab_info[1];
    float recip = (float)(1.0 / (double)hh);  FP_BAR(recip);
    const float4 pl = pack[(size_t)f * NALL + i];
    const float xl = pl.x, yl = pl.y, zl = pl.z;
    const int   ti = __float_as_int(pl.w);
    const float* tabi = tab + (size_t)ti * (NTYPES * NSPLINE * 4);
    const int4 jj = ((const int4*)(nlist + (size_t)wid * 256))[lane];
    const int mj0 = jj.x < 0 ? 0 : jj.x, mj1 = jj.y < 0 ? 0 : jj.y;
    const int mj2 = jj.z < 0 ? 0 : jj.z, mj3 = jj.w < 0 ? 0 : jj.w;
    const size_t fb = (size_t)f * NALL;
    const float4 c0 = pack[fb + mj0], c1 = pack[fb + mj1];
    const float4 c2 = pack[fb + mj2], c3 = pack[fb + mj3];
    double esum = nb_energy_g(c0, jj.x >= 0, xl, yl, zl, rmin, recip, tabi)
                + nb_energy_g(c1, jj.y >= 0, xl, yl, zl, rmin, recip, tabi)
                + nb_energy_g(c2, jj.z >= 0, xl, yl, zl, rmin, recip, tabi)
                + nb_energy_g(c3, jj.w >= 0, xl, yl, zl, rmin, recip, tabi);
#pragma unroll
    for (int off = 16; off >= 1; off >>= 1)
        esum += __shfl_xor(esum, off, 64);
    if ((lane & 31) == 0) out[gloc] = (float)(0.5 * esum);
}

extern "C" void kernel_launch(void* const* d_in, const int* in_sizes, int n_in,
                              void* d_out, int out_size, void* d_ws, size_t ws_size,
                              hipStream_t stream)
{
    const float* coord   = (const float*)d_in[0];   // (8,16384,3) f32
    const float* tab     = (const float*)d_in[1];   // (4,4,2000,4) f32
    const float* tabinfo = (const float*)d_in[2];   // (4,) f32
    const int*   atype   = (const int*)d_in[3];     // (8,16384) int32
    const int*   nlist   = (const int*)d_in[4];     // (8,8192,128) int32
    float* out  = (float*)d_out;                    // (8,8192,1) f32

    // ws layout (disjoint):
    //   pack  @ 0        2 MB   (8*16384*16)
    //   perm  @ 2 MB     1 MB   (32*8192*4)
    //   cnts  @ 3 MB     128 B  (4 KB slot)
    //   offs  @ 3 MB+4K  1 MB   (65536*16)
    //   cl16  @ 4 MB+4K  16 MB  (65536*128*2)
    float4* pack = (float4*)d_ws;
    int*    perm = (int*)((char*)d_ws + 2 * 1024 * 1024);
    int*    cnts = (int*)((char*)d_ws + 3 * 1024 * 1024);
    int4*   offs = (int4*)((char*)d_ws + 3 * 1024 * 1024 + 4096);
    ushort* cl16 = (ushort*)((char*)d_ws + 4 * 1024 * 1024 + 4096);
    const size_t need3 = 20 * 1024 * 1024 + 8192;
    const size_t need1 = 3 * 1024 * 1024 + 128;

    pack_kernel<<<(NFRAMES * NALL) / 256, 256, 0, stream>>>(coord, atype, pack,
                                                            cnts, out);
    if (ws_size >= need3) {
        bucket_kernel<<<(NFRAMES * NLOC) / 256, 256, 0, stream>>>(atype, perm,
                                                                  cnts);
        compact_kernel<<<(NFRAMES * NLOC) / 8, 256, 0, stream>>>(nlist, cl16,
                                                                 offs);
        pairtab_stream_kernel<<<NFRAMES * NTYPES * NCHUNK * SLICES, 1024, 0,
                                stream>>>(
            pack, tab, tabinfo, cl16, offs, perm, cnts, out);
    } else if (ws_size >= need1) {
        bucket_kernel<<<(NFRAMES * NLOC) / 256, 256, 0, stream>>>(atype, perm,
                                                                  cnts);
        pairtab_lds_kernel<<<NFRAMES * NTYPES * KBLK, 1024, 0, stream>>>(
            pack, tab, tabinfo, nlist, perm, cnts, out);
    } else {
        pairtab_kernel<<<(NFRAMES * NLOC) / 8, 256, 0, stream>>>(
            pack, tab, tabinfo, nlist, out);
    }
}

// Round 4
// 130.653 us; speedup vs baseline: 1.2220x; 1.2220x over previous
//
#include <hip/hip_runtime.h>

// Problem constants: nframes=8, nloc=8192, nnei=128, nall=16384, ntypes=4,
// nspline=2000. rmin=0, hh=f32(0.005), rcut=6.0.
constexpr int NFRAMES = 8;
constexpr int NLOC    = 8192;
constexpr int NNEI    = 128;
constexpr int NALL    = 16384;
constexpr int NTYPES  = 4;
constexpr int NSPLINE = 2000;
constexpr int KLIVE   = 1200;   // rr<6 => uu=rr*200<1200 => live bins [0,1200)
constexpr int KBLK    = 8;      // old lds kernel: chunks per bucket

// chunk-in-grid parameters
constexpr int CHUNK   = 4096;         // atoms per staged pack chunk (64 KiB)
constexpr int NCHUNK  = NALL / CHUNK; // 4
constexpr int SLICES  = 2;            // 32 buckets x 4 chunks x 2 = 256 blocks

// Opaque dataflow barrier: keeps the verified f32 rounding chain intact.
#define FP_BAR(x) asm volatile("" : "+v"(x))

__global__ __launch_bounds__(256) void pack_kernel(
    const float* __restrict__ coord, const int* __restrict__ atype,
    float4* __restrict__ pack, int* __restrict__ cnts,
    float* __restrict__ outz)
{
    int t = blockIdx.x * 256 + threadIdx.x;   // grid sized exactly (131072)
    if (blockIdx.x == 0 && threadIdx.x < NFRAMES * NTYPES) cnts[threadIdx.x] = 0;
    if (t < NFRAMES * NLOC) outz[t] = 0.f;    // out is atomic-accumulated
    float4 v;
    v.x = coord[3 * (size_t)t + 0];
    v.y = coord[3 * (size_t)t + 1];
    v.z = coord[3 * (size_t)t + 2];
    v.w = __int_as_float(atype[t]);
    pack[t] = v;
}

// Two-level aggregation (r14, ~3us): LDS histogram, 1 global atomic per
// (block,type), then scatter.
__global__ __launch_bounds__(256) void bucket_kernel(
    const int* __restrict__ atype, int* __restrict__ perm,
    int* __restrict__ cnts)
{
    __shared__ int hist[NTYPES];
    __shared__ int base[NTYPES];
    const int t = blockIdx.x * 256 + threadIdx.x;   // 0..65535
    const int f = t >> 13;                          // block-uniform (256|8192)
    const int i = t & (NLOC - 1);
    const int ty = atype[(size_t)f * NALL + i];

    if (threadIdx.x < NTYPES) hist[threadIdx.x] = 0;
    __syncthreads();
    const int my_off = atomicAdd(&hist[ty], 1);     // LDS atomic (fast)
    __syncthreads();
    if (threadIdx.x < NTYPES)
        base[threadIdx.x] = atomicAdd(&cnts[f * NTYPES + threadIdx.x],
                                      hist[threadIdx.x]);
    __syncthreads();
    perm[(size_t)(f * NTYPES + ty) * NLOC + base[ty] + my_off] = i;
}

// compact: one 32-lane half per row; int4 loads (4 comps/lane), ballot
// partition by chunk into an LDS row buffer, coalesced int4 flush. Output
// row = valid neighbors grouped by chunk (j>>12), invalid dropped, stored as
// ushort within-chunk index (j&4095). Order within a sublist is irrelevant
// (f64 accumulation). offs[row] = 4x packed (beg | end<<16) per chunk.
__global__ __launch_bounds__(256) void compact_kernel(
    const int* __restrict__ nlist, ushort* __restrict__ cl,
    int4* __restrict__ offs)
{
    __shared__ alignas(16) ushort srow[8][128];
    const int hr  = threadIdx.x >> 5;               // half-row 0..7
    const int lih = threadIdx.x & 31;
    const int w   = blockIdx.x * 8 + hr;            // row 0..65535
    const int* __restrict__ row = nlist + (size_t)w * NNEI;
    const int4 j4 = ((const int4*)row)[lih];        // comps 4*lih..4*lih+3
    const uint lt = (1u << lih) - 1u;
    const int hsh = (hr & 1) * 32;                  // this half's ballot shift
    int base = 0;
    int e[NCHUNK];
#pragma unroll
    for (int c = 0; c < NCHUNK; ++c) {
        const bool m0 = (j4.x >= 0) && ((j4.x >> 12) == c);
        const bool m1 = (j4.y >= 0) && ((j4.y >> 12) == c);
        const bool m2 = (j4.z >= 0) && ((j4.z >> 12) == c);
        const bool m3 = (j4.w >= 0) && ((j4.w >> 12) == c);
        const uint b0 = (uint)(__ballot(m0) >> hsh);
        const uint b1 = (uint)(__ballot(m1) >> hsh);
        const uint b2 = (uint)(__ballot(m2) >> hsh);
        const uint b3 = (uint)(__ballot(m3) >> hsh);
        const int n0 = __popc(b0), n1 = __popc(b1), n2 = __popc(b2);
        if (m0) srow[hr][base + __popc(b0 & lt)] = (ushort)(j4.x & (CHUNK - 1));
        if (m1) srow[hr][base + n0 + __popc(b1 & lt)] =
            (ushort)(j4.y & (CHUNK - 1));
        if (m2) srow[hr][base + n0 + n1 + __popc(b2 & lt)] =
            (ushort)(j4.z & (CHUNK - 1));
        if (m3) srow[hr][base + n0 + n1 + n2 + __popc(b3 & lt)] =
            (ushort)(j4.w & (CHUNK - 1));
        base += n0 + n1 + n2 + __popc(b3);
        e[c] = base;
    }
    __syncthreads();   // LDS scatter visible to flush lanes
    if (lih < 16)
        ((int4*)(cl + (size_t)w * NNEI))[lih] = ((const int4*)srow[hr])[lih];
    if (lih == 0)
        offs[w] = make_int4((int)((uint)e[0] << 16),
                            (int)(((uint)e[1] << 16) | (uint)e[0]),
                            (int)(((uint)e[2] << 16) | (uint)e[1]),
                            (int)(((uint)e[3] << 16) | (uint)e[2]));
}

// VERIFIED ref chain (r11, absmax 3.8e-6 — DO NOT TOUCH):
//   ss = fma(dz,dz, fma(dx,dx, dy*dy)); rr = CR sqrtf; uu = rr * f32(1/hh);
//   idx = trunc(uu); poly/sum in f64 (post-bin). Energy zero iff
//   !valid | rr>=6; live => idx in [0,1199].
// Invalid lanes pass c={0,0,0,0}: dx..ss are finite, valid=false skips ltab.
__device__ __forceinline__ double nb_energy_lds(
    float4 c, bool valid, float xl, float yl, float zl,
    float rmin, float recip, const float4* __restrict__ ltab)
{
    float dx = c.x - xl;  FP_BAR(dx);
    float dy = c.y - yl;  FP_BAR(dy);
    float dz = c.z - zl;  FP_BAR(dz);
    float my = dy * dy;                    FP_BAR(my);
    float t1 = __builtin_fmaf(dx, dx, my); FP_BAR(t1);   // canonical inner
    float ss = __builtin_fmaf(dz, dz, t1); FP_BAR(ss);
    float rr = sqrtf(ss);                  FP_BAR(rr);   // CR
    float num = rr - rmin;               FP_BAR(num);    // rmin=0: num==rr
    float uu  = num * recip;             FP_BAR(uu);     // recip-mul form
    double e = 0.0;
    if (valid && rr < 6.0f) {
        int    idx = (int)uu;                // in [0,1199] here
        double t   = (double)uu - (double)idx;           // exact (Sterbenz)
        int    tj  = __float_as_int(c.w);
        float4 cf  = ltab[tj * KLIVE + idx];             // ds_read_b128
        e = (((double)cf.x * t + (double)cf.y) * t + (double)cf.z) * t
            + (double)cf.w;
    }
    return e;
}

// r20 main kernel: lane-per-loc, zero cross-lane ops in the hot path.
// Block = (bucket, chunk, slice): stages ltab (76.8KB) + ONE cpack chunk
// (64KB). Each LANE owns a loc: reads its chunk sublist via aligned int4
// loads (8 ushorts each, statically unrolled -> compile-time reg indices),
// gathers cpack/ltab from LDS, accumulates in a private f64 register, and
// emits ONE f32 atomicAdd per (loc,chunk) (distinct addresses; f32-atomic
// chunk combine verified r19, absmax 3.8e-6). No shfl/ballot/butterfly —
// r18/r19 showed cross-lane machinery per ~26-entry sublist costs more than
// the TA gathers it replaces.
__global__ __launch_bounds__(1024) void pairtab_lane_kernel(
    const float4* __restrict__ pack,
    const float*  __restrict__ tab,       // [NTYPES][NTYPES][NSPLINE][4]
    const float*  __restrict__ tab_info,  // [rmin, hh, nspline, ntypes]
    const ushort* __restrict__ cl,        // chunk-compacted neighbor rows
    const uint*   __restrict__ offp,      // per-row packed (beg|end<<16) x4
    const int*    __restrict__ perm,      // [32][NLOC] bucketed loc ids
    const int*    __restrict__ cnts,      // [32]
    float*        __restrict__ out)       // [NFRAMES][NLOC], pre-zeroed
{
    __shared__ float4 ltab[NTYPES * KLIVE];   // 76800 B
    __shared__ float4 cpack[CHUNK];           // 65536 B  (142336 total)

    const int blk    = blockIdx.x;
    const int slice  = blk & (SLICES - 1);
    const int c      = (blk >> 1) & (NCHUNK - 1);
    const int bucket = blk >> 3;              // 0..31
    const int f  = bucket >> 2;
    const int ti = bucket & 3;

    // stage tab[ti][tj][0..1199][:] -> ltab[tj*1200+k] (coalesced float4)
    const float4* tsrc = (const float4*)tab + (size_t)ti * (NTYPES * NSPLINE);
    for (int idx = threadIdx.x; idx < NTYPES * KLIVE; idx += 1024) {
        int tj = idx / KLIVE;
        int k  = idx - tj * KLIVE;
        ltab[idx] = tsrc[tj * NSPLINE + k];
    }
    // stage this block's pack chunk
    {
        const float4* psrc = pack + (size_t)f * NALL + c * CHUNK;
        for (int k = threadIdx.x; k < CHUNK; k += 1024) cpack[k] = psrc[k];
    }
    __syncthreads();

    const float rmin = tab_info[0];
    const float hh   = tab_info[1];
    // CR f32 reciprocal via f64 + single rounding == f32 divide(1,hh) == 200.0f
    float recip = (float)(1.0 / (double)hh);  FP_BAR(recip);

    const int cnt = cnts[bucket];
    const size_t fb = (size_t)f * NALL;
    const int*    __restrict__ permb = perm + (size_t)bucket * NLOC;
    const ushort* __restrict__ clf   = cl   + (size_t)f * NLOC * NNEI;
    const float4 zero4 = make_float4(0.f, 0.f, 0.f, 0.f);

    // lane-private loop: s = 2k+slice, one loc per lane, no cross-lane ops
    for (int k = threadIdx.x; 2 * k + slice < cnt; k += 1024) {
        const int s   = 2 * k + slice;
        const int loc = permb[s];
        const uint be = offp[((size_t)f * NLOC + loc) * NCHUNK + c];
        const int beg = (int)(be & 0xffffu);
        const int end = (int)(be >> 16);
        const float4 pl = pack[fb + loc];
        const ushort* __restrict__ crow = clf + (size_t)loc * NNEI;

        double acc = 0.0;
        for (int w = (beg & ~7); w < end; w += 8) {
            const int4 v = *(const int4*)(crow + w);   // 16B aligned
            // 8 entries, compile-time indices (no dynamic reg indexing)
#define DO_ENT(word, sh, o)                                                  \
            {                                                                \
                const int  ei = w + (o);                                     \
                const bool lv = (ei >= beg) && (ei < end);                   \
                const int  us = ((word) >> (sh)) & 0xffff;                   \
                float4 cc = zero4;                                           \
                if (lv) cc = cpack[us];            /* LDS gather */          \
                acc += nb_energy_lds(cc, lv, pl.x, pl.y, pl.z, rmin, recip,  \
                                     ltab);                                  \
            }
            DO_ENT(v.x,  0, 0) DO_ENT(v.x, 16, 1)
            DO_ENT(v.y,  0, 2) DO_ENT(v.y, 16, 3)
            DO_ENT(v.z,  0, 4) DO_ENT(v.z, 16, 5)
            DO_ENT(v.w,  0, 6) DO_ENT(v.w, 16, 7)
#undef DO_ENT
        }
        atomicAdd(&out[(size_t)f * NLOC + loc], (float)(0.5 * acc));
    }
}

// -------- r16 kernel (kept as mid-ws fallback) --------
__global__ __launch_bounds__(1024, 8) void pairtab_lds_kernel(
    const float4* __restrict__ pack,
    const float*  __restrict__ tab,
    const float*  __restrict__ tab_info,
    const int*    __restrict__ nlist,
    const int*    __restrict__ perm,
    const int*    __restrict__ cnts,
    float*        __restrict__ out)
{
    __shared__ float4 ltab[NTYPES * KLIVE];   // 76800 B

    const int bucket = blockIdx.x >> 3;       // / KBLK
    const int chunk  = blockIdx.x & (KBLK - 1);
    const int f  = bucket >> 2;
    const int ti = bucket & 3;

    const float4* tsrc = (const float4*)tab + (size_t)ti * (NTYPES * NSPLINE);
    for (int idx = threadIdx.x; idx < NTYPES * KLIVE; idx += 1024) {
        int tj = idx / KLIVE;
        int k  = idx - tj * KLIVE;
        ltab[idx] = tsrc[tj * NSPLINE + k];
    }
    __syncthreads();

    const float rmin = tab_info[0];
    const float hh   = tab_info[1];
    float recip = (float)(1.0 / (double)hh);  FP_BAR(recip);

    const int cnt  = cnts[bucket];
    const int lane = threadIdx.x & 63;
    const int wave = (int)(threadIdx.x >> 6); // 0..15
    const int half = lane >> 5;
    const int lih  = lane & 31;
    const size_t fb = (size_t)f * NALL;
    const int* __restrict__ permb = perm + (size_t)bucket * NLOC;
    const int* __restrict__ nlf   = nlist + (size_t)f * NLOC * NNEI;
    const float4 zero4 = make_float4(0.f, 0.f, 0.f, 0.f);

    for (int s0 = chunk * 32; s0 < cnt; s0 += KBLK * 32) {
        const int s = s0 + wave * 2 + half;
        const bool active = s < cnt;          // uniform per 32-lane half
        const int loc = active ? permb[s] : 0;

        const float4 pl = pack[fb + loc];     // half-uniform broadcast
        const float xl = pl.x, yl = pl.y, zl = pl.z;

        const int4 jj = ((const int4*)(nlf + (size_t)loc * NNEI))[lih];

        float4 c0 = zero4, c1 = zero4, c2 = zero4, c3 = zero4;
        if (jj.x >= 0) c0 = pack[fb + jj.x];
        if (jj.y >= 0) c1 = pack[fb + jj.y];
        if (jj.z >= 0) c2 = pack[fb + jj.z];
        if (jj.w >= 0) c3 = pack[fb + jj.w];

        double esum = nb_energy_lds(c0, jj.x >= 0, xl, yl, zl, rmin, recip, ltab)
                    + nb_energy_lds(c1, jj.y >= 0, xl, yl, zl, rmin, recip, ltab)
                    + nb_energy_lds(c2, jj.z >= 0, xl, yl, zl, rmin, recip, ltab)
                    + nb_energy_lds(c3, jj.w >= 0, xl, yl, zl, rmin, recip, ltab);

#pragma unroll
        for (int off = 16; off >= 1; off >>= 1)
            esum += __shfl_xor(esum, off, 64);

        if (active && lih == 0) out[(size_t)f * NLOC + loc] = (float)(0.5 * esum);
    }
}

// -------- r12 fallback (used only if ws_size is too small) --------
__device__ __forceinline__ double nb_energy_g(
    float4 c, bool valid, float xl, float yl, float zl,
    float rmin, float recip, const float* __restrict__ tabi)
{
    float dx = c.x - xl;  FP_BAR(dx);
    float dy = c.y - yl;  FP_BAR(dy);
    float dz = c.z - zl;  FP_BAR(dz);
    float my = dy * dy;                    FP_BAR(my);
    float t1 = __builtin_fmaf(dx, dx, my); FP_BAR(t1);
    float ss = __builtin_fmaf(dz, dz, t1); FP_BAR(ss);
    float rr = sqrtf(ss);                  FP_BAR(rr);
    float num = rr - rmin;               FP_BAR(num);
    float uu  = num * recip;             FP_BAR(uu);
    int   idx = (int)uu;
    double t  = (double)uu - (double)idx;
    int clip  = idx < 0 ? 0 : (idx > NSPLINE - 1 ? NSPLINE - 1 : idx);
    int tj    = __float_as_int(c.w);
    const float4 coef =
        *(const float4*)(tabi + (((size_t)tj * NSPLINE + clip) << 2));
    double e = (((double)coef.x * t + (double)coef.y) * t + (double)coef.z) * t
               + (double)coef.w;
    bool zero = (!valid) | (idx > NSPLINE) | (rr >= 6.0f);
    return zero ? 0.0 : e;
}

__global__ __launch_bounds__(256) void pairtab_kernel(
    const float4* __restrict__ pack, const float* __restrict__ tab,
    const float* __restrict__ tab_info, const int* __restrict__ nlist,
    float* __restrict__ out)
{
    const int lane = threadIdx.x & 63;
    const int wid  = (blockIdx.x * 256 + threadIdx.x) >> 6;
    const int half = lane >> 5;
    const int gloc = 2 * wid + half;
    const int f = gloc >> 13;
    const int i = gloc & (NLOC - 1);
    const float rmin = tab_info[0];
    const float hh   = tab_info[1];
    float recip = (float)(1.0 / (double)hh);  FP_BAR(recip);
    const float4 pl = pack[(size_t)f * NALL + i];
    const float xl = pl.x, yl = pl.y, zl = pl.z;
    const int   ti = __float_as_int(pl.w);
    const float* tabi = tab + (size_t)ti * (NTYPES * NSPLINE * 4);
    const int4 jj = ((const int4*)(nlist + (size_t)wid * 256))[lane];
    const int mj0 = jj.x < 0 ? 0 : jj.x, mj1 = jj.y < 0 ? 0 : jj.y;
    const int mj2 = jj.z < 0 ? 0 : jj.z, mj3 = jj.w < 0 ? 0 : jj.w;
    const size_t fb = (size_t)f * NALL;
    const float4 c0 = pack[fb + mj0], c1 = pack[fb + mj1];
    const float4 c2 = pack[fb + mj2], c3 = pack[fb + mj3];
    double esum = nb_energy_g(c0, jj.x >= 0, xl, yl, zl, rmin, recip, tabi)
                + nb_energy_g(c1, jj.y >= 0, xl, yl, zl, rmin, recip, tabi)
                + nb_energy_g(c2, jj.z >= 0, xl, yl, zl, rmin, recip, tabi)
                + nb_energy_g(c3, jj.w >= 0, xl, yl, zl, rmin, recip, tabi);
#pragma unroll
    for (int off = 16; off >= 1; off >>= 1)
        esum += __shfl_xor(esum, off, 64);
    if ((lane & 31) == 0) out[gloc] = (float)(0.5 * esum);
}

extern "C" void kernel_launch(void* const* d_in, const int* in_sizes, int n_in,
                              void* d_out, int out_size, void* d_ws, size_t ws_size,
                              hipStream_t stream)
{
    const float* coord   = (const float*)d_in[0];   // (8,16384,3) f32
    const float* tab     = (const float*)d_in[1];   // (4,4,2000,4) f32
    const float* tabinfo = (const float*)d_in[2];   // (4,) f32
    const int*   atype   = (const int*)d_in[3];     // (8,16384) int32
    const int*   nlist   = (const int*)d_in[4];     // (8,8192,128) int32
    float* out  = (float*)d_out;                    // (8,8192,1) f32

    // ws layout (disjoint):
    //   pack  @ 0        2 MB   (8*16384*16)
    //   perm  @ 2 MB     1 MB   (32*8192*4)
    //   cnts  @ 3 MB     128 B  (4 KB slot)
    //   offs  @ 3 MB+4K  1 MB   (65536*16, packed beg|end<<16 x4)
    //   cl16  @ 4 MB+4K  16 MB  (65536*128*2)
    float4* pack = (float4*)d_ws;
    int*    perm = (int*)((char*)d_ws + 2 * 1024 * 1024);
    int*    cnts = (int*)((char*)d_ws + 3 * 1024 * 1024);
    int4*   offs = (int4*)((char*)d_ws + 3 * 1024 * 1024 + 4096);
    ushort* cl16 = (ushort*)((char*)d_ws + 4 * 1024 * 1024 + 4096);
    const size_t need3 = 20 * 1024 * 1024 + 8192;
    const size_t need1 = 3 * 1024 * 1024 + 128;

    pack_kernel<<<(NFRAMES * NALL) / 256, 256, 0, stream>>>(coord, atype, pack,
                                                            cnts, out);
    if (ws_size >= need3) {
        bucket_kernel<<<(NFRAMES * NLOC) / 256, 256, 0, stream>>>(atype, perm,
                                                                  cnts);
        compact_kernel<<<(NFRAMES * NLOC) / 8, 256, 0, stream>>>(nlist, cl16,
                                                                 offs);
        pairtab_lane_kernel<<<NFRAMES * NTYPES * NCHUNK * SLICES, 1024, 0,
                              stream>>>(
            pack, tab, tabinfo, cl16, (const uint*)offs, perm, cnts, out);
    } else if (ws_size >= need1) {
        bucket_kernel<<<(NFRAMES * NLOC) / 256, 256, 0, stream>>>(atype, perm,
                                                                  cnts);
        pairtab_lds_kernel<<<NFRAMES * NTYPES * KBLK, 1024, 0, stream>>>(
            pack, tab, tabinfo, nlist, perm, cnts, out);
    } else {
        pairtab_kernel<<<(NFRAMES * NLOC) / 8, 256, 0, stream>>>(
            pack, tab, tabinfo, nlist, out);
    }
}

// Round 5
// 115.785 us; speedup vs baseline: 1.3789x; 1.1284x over previous
//
#include <hip/hip_runtime.h>

// Problem constants: nframes=8, nloc=8192, nnei=128, nall=16384, ntypes=4,
// nspline=2000. rmin=0, hh=f32(0.005), rcut=6.0.
constexpr int NFRAMES = 8;
constexpr int NLOC    = 8192;
constexpr int NNEI    = 128;
constexpr int NALL    = 16384;
constexpr int NTYPES  = 4;
constexpr int NSPLINE = 2000;
constexpr int KLIVE   = 1200;   // rr<6 => uu=rr*200<1200 => live bins [0,1200)
constexpr int KBLK    = 8;      // chunks per bucket: 256 blocks = 1/CU

// Opaque dataflow barrier: keeps the verified f32 rounding chain intact.
#define FP_BAR(x) asm volatile("" : "+v"(x))

// r21: pack+bucket fused (saves one dispatch + one atype pass). cnts is
// zeroed by a 128B hipMemsetAsync enqueued before this kernel (stream
// ordering guarantees init-before-atomics; r16's in-kernel zeroing relied
// on the separate pack launch completing first).
// Ghost blocks (i >= NLOC) are block-uniform: (NALL|256, NLOC|256).
__global__ __launch_bounds__(256) void pack_bucket_kernel(
    const float* __restrict__ coord, const int* __restrict__ atype,
    float4* __restrict__ pack, int* __restrict__ perm,
    int* __restrict__ cnts)
{
    __shared__ int hist[NTYPES];
    __shared__ int base[NTYPES];
    const int t = blockIdx.x * 256 + threadIdx.x;   // 0..131071 exact grid
    const int f = t >> 14;                          // NALL = 2^14 per frame
    const int i = t & (NALL - 1);
    const int ty = atype[t];

    float4 v;
    v.x = coord[3 * (size_t)t + 0];
    v.y = coord[3 * (size_t)t + 1];
    v.z = coord[3 * (size_t)t + 2];
    v.w = __int_as_float(ty);
    pack[t] = v;

    if (i >= NLOC) return;                          // whole-block uniform

    // two-level aggregation (r14): LDS histogram, 1 global atomic per
    // (block,type), then scatter.
    if (threadIdx.x < NTYPES) hist[threadIdx.x] = 0;
    __syncthreads();
    const int my_off = atomicAdd(&hist[ty], 1);     // LDS atomic (fast)
    __syncthreads();
    if (threadIdx.x < NTYPES)
        base[threadIdx.x] = atomicAdd(&cnts[f * NTYPES + threadIdx.x],
                                      hist[threadIdx.x]);
    __syncthreads();
    perm[(size_t)(f * NTYPES + ty) * NLOC + base[ty] + my_off] = i;
}

// VERIFIED ref chain (r11, absmax 3.8e-6 — DO NOT TOUCH):
//   ss = fma(dz,dz, fma(dx,dx, dy*dy)); rr = CR sqrtf; uu = rr * f32(1/hh);
//   idx = trunc(uu); poly/sum in f64 (post-bin). Energy zero iff
//   !valid | rr>=6; live => idx in [0,1199].
// Invalid lanes pass c={0,0,0,0}: dx..ss are finite, valid=false skips ltab.
__device__ __forceinline__ double nb_energy_lds(
    float4 c, bool valid, float xl, float yl, float zl,
    float rmin, float recip, const float4* __restrict__ ltab)
{
    float dx = c.x - xl;  FP_BAR(dx);
    float dy = c.y - yl;  FP_BAR(dy);
    float dz = c.z - zl;  FP_BAR(dz);
    float my = dy * dy;                    FP_BAR(my);
    float t1 = __builtin_fmaf(dx, dx, my); FP_BAR(t1);   // canonical inner
    float ss = __builtin_fmaf(dz, dz, t1); FP_BAR(ss);
    float rr = sqrtf(ss);                  FP_BAR(rr);   // CR
    float num = rr - rmin;               FP_BAR(num);    // rmin=0: num==rr
    float uu  = num * recip;             FP_BAR(uu);     // recip-mul form
    double e = 0.0;
    if (valid && rr < 6.0f) {
        int    idx = (int)uu;                // in [0,1199] here
        double t   = (double)uu - (double)idx;           // exact (Sterbenz)
        int    tj  = __float_as_int(c.w);
        float4 cf  = ltab[tj * KLIVE + idx];             // ds_read_b128
        e = (((double)cf.x * t + (double)cf.y) * t + (double)cf.z) * t
            + (double)cf.w;
    }
    return e;
}

// r16 model (fits r12-r20): time = scattered lane-requests x ~2.2cyc/CU
// (TA throughput ~0.45 lane-req/cyc), independent of waves & MLP. r17-r20
// structural replacements (LDS chunk gathers, lane-per-loc, shfl
// redistribution) all cost >= the TA they saved. This kernel is the
// verified best (47.2us @ ~10.5M lane-req: 6.7M exec-masked gathers +
// 2.1M nlist + 1.2M staging + broadcasts).
__global__ __launch_bounds__(1024, 8) void pairtab_lds_kernel(
    const float4* __restrict__ pack,
    const float*  __restrict__ tab,       // [NTYPES][NTYPES][NSPLINE][4]
    const float*  __restrict__ tab_info,  // [rmin, hh, nspline, ntypes]
    const int*    __restrict__ nlist,     // [NFRAMES][NLOC][NNEI] int32
    const int*    __restrict__ perm,      // [32][NLOC] bucketed loc ids
    const int*    __restrict__ cnts,      // [32]
    float*        __restrict__ out)       // [NFRAMES][NLOC]
{
    __shared__ float4 ltab[NTYPES * KLIVE];   // 76800 B

    const int bucket = blockIdx.x >> 3;       // / KBLK
    const int chunk  = blockIdx.x & (KBLK - 1);
    const int f  = bucket >> 2;
    const int ti = bucket & 3;

    // stage tab[ti][tj][0..1199][:] -> ltab[tj*1200+k] (coalesced float4)
    const float4* tsrc = (const float4*)tab + (size_t)ti * (NTYPES * NSPLINE);
    for (int idx = threadIdx.x; idx < NTYPES * KLIVE; idx += 1024) {
        int tj = idx / KLIVE;
        int k  = idx - tj * KLIVE;
        ltab[idx] = tsrc[tj * NSPLINE + k];
    }
    __syncthreads();

    const float rmin = tab_info[0];
    const float hh   = tab_info[1];
    // CR f32 reciprocal via f64 + single rounding == f32 divide(1,hh) == 200.0f
    float recip = (float)(1.0 / (double)hh);  FP_BAR(recip);

    const int cnt  = cnts[bucket];
    const int lane = threadIdx.x & 63;
    const int wave = (int)(threadIdx.x >> 6); // 0..15
    const int half = lane >> 5;
    const int lih  = lane & 31;
    const size_t fb = (size_t)f * NALL;
    const int* __restrict__ permb = perm + (size_t)bucket * NLOC;
    const int* __restrict__ nlf   = nlist + (size_t)f * NLOC * NNEI;
    const float4 zero4 = make_float4(0.f, 0.f, 0.f, 0.f);

    // each block iteration covers 32 locs: 16 waves x 2 halves x 1 loc
    for (int s0 = chunk * 32; s0 < cnt; s0 += KBLK * 32) {
        const int s = s0 + wave * 2 + half;
        const bool active = s < cnt;          // uniform per 32-lane half
        const int loc = active ? permb[s] : 0;

        const float4 pl = pack[fb + loc];     // half-uniform broadcast
        const float xl = pl.x, yl = pl.y, zl = pl.z;

        // lanes of this half read their loc's 128 neighbor ids (int4/lane)
        const int4 jj = ((const int4*)(nlf + (size_t)loc * NNEI))[lih];

        // exec-masked gathers: invalid lanes issue NO TA request
        float4 c0 = zero4, c1 = zero4, c2 = zero4, c3 = zero4;
        if (jj.x >= 0) c0 = pack[fb + jj.x];
        if (jj.y >= 0) c1 = pack[fb + jj.y];
        if (jj.z >= 0) c2 = pack[fb + jj.z];
        if (jj.w >= 0) c3 = pack[fb + jj.w];

        double esum = nb_energy_lds(c0, jj.x >= 0, xl, yl, zl, rmin, recip, ltab)
                    + nb_energy_lds(c1, jj.y >= 0, xl, yl, zl, rmin, recip, ltab)
                    + nb_energy_lds(c2, jj.z >= 0, xl, yl, zl, rmin, recip, ltab)
                    + nb_energy_lds(c3, jj.w >= 0, xl, yl, zl, rmin, recip, ltab);

        // butterfly within each 32-lane half
#pragma unroll
        for (int off = 16; off >= 1; off >>= 1)
            esum += __shfl_xor(esum, off, 64);

        if (active && lih == 0) out[(size_t)f * NLOC + loc] = (float)(0.5 * esum);
    }
}

// -------- r12 fallback (used only if ws_size is too small) --------
__device__ __forceinline__ double nb_energy_g(
    float4 c, bool valid, float xl, float yl, float zl,
    float rmin, float recip, const float* __restrict__ tabi)
{
    float dx = c.x - xl;  FP_BAR(dx);
    float dy = c.y - yl;  FP_BAR(dy);
    float dz = c.z - zl;  FP_BAR(dz);
    float my = dy * dy;                    FP_BAR(my);
    float t1 = __builtin_fmaf(dx, dx, my); FP_BAR(t1);
    float ss = __builtin_fmaf(dz, dz, t1); FP_BAR(ss);
    float rr = sqrtf(ss);                  FP_BAR(rr);
    float num = rr - rmin;               FP_BAR(num);
    float uu  = num * recip;             FP_BAR(uu);
    int   idx = (int)uu;
    double t  = (double)uu - (double)idx;
    int clip  = idx < 0 ? 0 : (idx > NSPLINE - 1 ? NSPLINE - 1 : idx);
    int tj    = __float_as_int(c.w);
    const float4 coef =
        *(const float4*)(tabi + (((size_t)tj * NSPLINE + clip) << 2));
    double e = (((double)coef.x * t + (double)coef.y) * t + (double)coef.z) * t
               + (double)coef.w;
    bool zero = (!valid) | (idx > NSPLINE) | (rr >= 6.0f);
    return zero ? 0.0 : e;
}

__global__ __launch_bounds__(256) void pack_only_kernel(
    const float* __restrict__ coord, const int* __restrict__ atype,
    float4* __restrict__ pack)
{
    int t = blockIdx.x * 256 + threadIdx.x;   // grid sized exactly
    float4 v;
    v.x = coord[3 * (size_t)t + 0];
    v.y = coord[3 * (size_t)t + 1];
    v.z = coord[3 * (size_t)t + 2];
    v.w = __int_as_float(atype[t]);
    pack[t] = v;
}

__global__ __launch_bounds__(256) void pairtab_kernel(
    const float4* __restrict__ pack, const float* __restrict__ tab,
    const float* __restrict__ tab_info, const int* __restrict__ nlist,
    float* __restrict__ out)
{
    const int lane = threadIdx.x & 63;
    const int wid  = (blockIdx.x * 256 + threadIdx.x) >> 6;
    const int half = lane >> 5;
    const int gloc = 2 * wid + half;
    const int f = gloc >> 13;
    const int i = gloc & (NLOC - 1);
    const float rmin = tab_info[0];
    const float hh   = tab_info[1];
    float recip = (float)(1.0 / (double)hh);  FP_BAR(recip);
    const float4 pl = pack[(size_t)f * NALL + i];
    const float xl = pl.x, yl = pl.y, zl = pl.z;
    const int   ti = __float_as_int(pl.w);
    const float* tabi = tab + (size_t)ti * (NTYPES * NSPLINE * 4);
    const int4 jj = ((const int4*)(nlist + (size_t)wid * 256))[lane];
    const int mj0 = jj.x < 0 ? 0 : jj.x, mj1 = jj.y < 0 ? 0 : jj.y;
    const int mj2 = jj.z < 0 ? 0 : jj.z, mj3 = jj.w < 0 ? 0 : jj.w;
    const size_t fb = (size_t)f * NALL;
    const float4 c0 = pack[fb + mj0], c1 = pack[fb + mj1];
    const float4 c2 = pack[fb + mj2], c3 = pack[fb + mj3];
    double esum = nb_energy_g(c0, jj.x >= 0, xl, yl, zl, rmin, recip, tabi)
                + nb_energy_g(c1, jj.y >= 0, xl, yl, zl, rmin, recip, tabi)
                + nb_energy_g(c2, jj.z >= 0, xl, yl, zl, rmin, recip, tabi)
                + nb_energy_g(c3, jj.w >= 0, xl, yl, zl, rmin, recip, tabi);
#pragma unroll
    for (int off = 16; off >= 1; off >>= 1)
        esum += __shfl_xor(esum, off, 64);
    if ((lane & 31) == 0) out[gloc] = (float)(0.5 * esum);
}

extern "C" void kernel_launch(void* const* d_in, const int* in_sizes, int n_in,
                              void* d_out, int out_size, void* d_ws, size_t ws_size,
                              hipStream_t stream)
{
    const float* coord   = (const float*)d_in[0];   // (8,16384,3) f32
    const float* tab     = (const float*)d_in[1];   // (4,4,2000,4) f32
    const float* tabinfo = (const float*)d_in[2];   // (4,) f32
    const int*   atype   = (const int*)d_in[3];     // (8,16384) int32
    const int*   nlist   = (const int*)d_in[4];     // (8,8192,128) int32
    float* out  = (float*)d_out;                    // (8,8192,1) f32

    // ws layout: pack 2MB | perm 1MB | cnts 128B
    float4* pack = (float4*)d_ws;
    int*    perm = (int*)((char*)d_ws + 2 * 1024 * 1024);
    int*    cnts = (int*)((char*)d_ws + 3 * 1024 * 1024);
    const size_t need = 3 * 1024 * 1024 + 128;

    if (ws_size >= need) {
        // 128B async memset (stream-ordered before the fused kernel's atomics)
        hipMemsetAsync(cnts, 0, NFRAMES * NTYPES * sizeof(int), stream);
        pack_bucket_kernel<<<(NFRAMES * NALL) / 256, 256, 0, stream>>>(
            coord, atype, pack, perm, cnts);
        pairtab_lds_kernel<<<NFRAMES * NTYPES * KBLK, 1024, 0, stream>>>(
            pack, tab, tabinfo, nlist, perm, cnts, out);
    } else {
        pack_only_kernel<<<(NFRAMES * NALL) / 256, 256, 0, stream>>>(
            coord, atype, (float4*)d_ws);
        pairtab_kernel<<<(NFRAMES * NLOC) / 8, 256, 0, stream>>>(
            (const float4*)d_ws, tab, tabinfo, nlist, out);
    }
}